// Round 13
// baseline (698.857 us; speedup 1.0000x reference)
//
#include <hip/hip_runtime.h>

typedef __attribute__((ext_vector_type(8))) short bf16x8;
typedef __attribute__((ext_vector_type(4))) float f32x4;
typedef __attribute__((ext_vector_type(2))) float f32x2;

#define HID 768
#define NH 12
#define HD 64

#if defined(__has_builtin)
#  if __has_builtin(__builtin_amdgcn_exp2f)
#    define EXP2(x) __builtin_amdgcn_exp2f(x)
#  endif
#endif
#ifndef EXP2
#  define EXP2(x) exp2f(x)
#endif

// q pre-scale: HEAD_DIM^-0.5 * log2(e)  -> scores land in log2 domain
#define QSCALE 0.18033688011112042f

__device__ inline float b2f(unsigned short x) {
  return __builtin_bit_cast(float, ((unsigned)x) << 16);
}
__device__ inline unsigned short f2b(float f) {
  unsigned u = __builtin_bit_cast(unsigned, f);
  u += 0x7fffu + ((u >> 16) & 1u);  // RNE
  return (unsigned short)(u >> 16);
}
// one packed bf16 dword -> 2 floats
__device__ inline f32x2 bf2f2(unsigned d) {
  f32x2 r;
  r[0] = __builtin_bit_cast(float, d << 16);
  r[1] = __builtin_bit_cast(float, d & 0xFFFF0000u);
  return r;
}

// ---------------- cast fp32 -> bf16 (both tensors, one launch) ----------------
__global__ __launch_bounds__(256) void cast_bf16_2(const float* __restrict__ in0,
                                                   const float* __restrict__ in1,
                                                   unsigned short* __restrict__ out0,
                                                   unsigned short* __restrict__ out1, int n4) {
  int t = blockIdx.x * 256 + threadIdx.x;
  if (t >= n4) return;
  const float* in = blockIdx.y ? in1 : in0;
  unsigned short* out = blockIdx.y ? out1 : out0;
  float4 v = ((const float4*)in)[t];
  ushort4 o;
  o.x = f2b(v.x); o.y = f2b(v.y); o.z = f2b(v.z); o.w = f2b(v.w);
  ((ushort4*)out)[t] = o;
}

// ---------------- weight prep: permute rows to head-major, cast bf16 ----------------
__global__ __launch_bounds__(256) void prep_weights(
    const float* __restrict__ Wq, const float* __restrict__ Wk,
    const float* __restrict__ Wv, const float* __restrict__ Wo,
    unsigned short* __restrict__ wq, unsigned short* __restrict__ wkv,
    unsigned short* __restrict__ wo) {
  int mat = blockIdx.y;
  int o = blockIdx.x * 256 + threadIdx.x;  // < 768*768
  int jrow = o / HID, c = o - jrow * HID;
  if (mat < 3) {
    int h = jrow >> 6, d = jrow & 63;
    const float* W = (mat == 0) ? Wq : ((mat == 1) ? Wk : Wv);
    float val = W[(d * NH + h) * HID + c];
    if (mat == 0) {
      wq[o] = f2b(val * QSCALE);
    } else if (mat == 1) {
      wkv[o] = f2b(val);
    } else {
      wkv[(size_t)HID * HID + o] = f2b(val);
    }
  } else {
    int h = c >> 6, d = c & 63;
    wo[o] = f2b(Wo[(size_t)jrow * HID + d * NH + h]);
  }
}

__global__ void prep_bias(const float* __restrict__ bq, const float* __restrict__ bk,
                          const float* __restrict__ bv, float* __restrict__ bqp,
                          float* __restrict__ bkvp) {
  int j = threadIdx.x;
  if (j >= HID) return;
  int h = j >> 6, d = j & 63, s = d * NH + h;
  bqp[j] = bq[s] * QSCALE;
  bkvp[j] = bk[s];
  bkvp[HID + j] = bv[s];
}

// ---------------- fused projection GEMM: q (by<6, htb) + kv (by>=6, hsb), one dispatch ----------------
__global__ __launch_bounds__(256) void gemm_proj(
    const unsigned short* __restrict__ Aq, const unsigned short* __restrict__ Akv,
    const unsigned short* __restrict__ Bq, const unsigned short* __restrict__ Bkv,
    const float* __restrict__ biasq, const float* __restrict__ biaskv,
    unsigned short* __restrict__ Cq, unsigned short* __restrict__ Ckv, int M) {
  __shared__ __align__(16) unsigned short As[2][128 * 32];
  __shared__ __align__(16) unsigned short Bs[2][128 * 32];
  const int K = HID;
  const int tid = threadIdx.x;
  const int lane = tid & 63;
  const int wid = tid >> 6;
  const int wr = wid >> 1, wc = wid & 1;
  const int l16 = lane & 15, kq = lane >> 4;

  int gx = gridDim.x, gy = gridDim.y;
  int nwg = gx * gy;
  int orig = blockIdx.y * gx + blockIdx.x;
  int bx, by;
  if ((nwg & 7) == 0) {
    int cpx = nwg >> 3;
    int swz = (orig & 7) * cpx + (orig >> 3);
    bx = swz / gy;
    by = swz - bx * gy;
  } else {
    bx = blockIdx.x;
    by = blockIdx.y;
  }
  const unsigned short* A;
  const unsigned short* B;
  const float* bias;
  unsigned short* C;
  int Nn, n0;
  if (by < 6) {
    A = Aq; B = Bq; bias = biasq; C = Cq; Nn = HID; n0 = by * 128;
  } else {
    A = Akv; B = Bkv; bias = biaskv; C = Ckv; Nn = 2 * HID; n0 = (by - 6) * 128;
  }
  const int m0 = bx * 128;

  f32x4 acc[4][4];
#pragma unroll
  for (int i = 0; i < 4; ++i)
#pragma unroll
    for (int j = 0; j < 4; ++j) acc[i][j] = (f32x4){0.f, 0.f, 0.f, 0.f};

  const int srow = tid >> 2;
  const int skg = tid & 3;
  const int scol = (skg ^ ((srow >> 1) & 3)) * 8;
  const int sbase = (tid & ~63) * 8;

  const unsigned short* Ag = A + (size_t)(m0 + srow) * K + scol;
  const unsigned short* Bg = B + (size_t)(n0 + srow) * K + scol;
  const int kqA0 = (kq ^ ((l16 >> 1) & 3)) * 8;

#define STAGE(buf, kk)                                                                              \
  do {                                                                                              \
    __builtin_amdgcn_global_load_lds((const __attribute__((address_space(1))) void*)(Ag + (kk)),    \
                                     (__attribute__((address_space(3))) void*)(&As[buf][0] + sbase), 16, 0, 0); \
    __builtin_amdgcn_global_load_lds((const __attribute__((address_space(1))) void*)(Ag + (size_t)64 * K + (kk)), \
                                     (__attribute__((address_space(3))) void*)(&As[buf][0] + 2048 + sbase), 16, 0, 0); \
    __builtin_amdgcn_global_load_lds((const __attribute__((address_space(1))) void*)(Bg + (kk)),    \
                                     (__attribute__((address_space(3))) void*)(&Bs[buf][0] + sbase), 16, 0, 0); \
    __builtin_amdgcn_global_load_lds((const __attribute__((address_space(1))) void*)(Bg + (size_t)64 * K + (kk)), \
                                     (__attribute__((address_space(3))) void*)(&Bs[buf][0] + 2048 + sbase), 16, 0, 0); \
  } while (0)

  STAGE(0, 0);
  __syncthreads();
  int cur = 0;
  for (int k0 = 0; k0 < K; k0 += 32) {
    if (k0 + 32 < K) STAGE(cur ^ 1, k0 + 32);
    bf16x8 af[4], bfr[4];
#pragma unroll
    for (int i = 0; i < 4; ++i) {
      int ra = wr * 64 + i * 16 + l16;
      af[i] = *(const bf16x8*)(&As[cur][0] + ra * 32 + kqA0);
      int rb = wc * 64 + i * 16 + l16;
      bfr[i] = *(const bf16x8*)(&Bs[cur][0] + rb * 32 + kqA0);
    }
#pragma unroll
    for (int mi = 0; mi < 4; ++mi)
#pragma unroll
      for (int ni = 0; ni < 4; ++ni)
        acc[mi][ni] = __builtin_amdgcn_mfma_f32_16x16x32_bf16(af[mi], bfr[ni], acc[mi][ni], 0, 0, 0);
    __syncthreads();
    cur ^= 1;
  }
#undef STAGE

#pragma unroll
  for (int mi = 0; mi < 4; ++mi) {
    int grow = m0 + wr * 64 + mi * 16 + kq * 4;
#pragma unroll
    for (int ni = 0; ni < 4; ++ni) {
      int gcol = n0 + wc * 64 + ni * 16 + l16;
      float bv_ = bias[gcol];
#pragma unroll
      for (int r = 0; r < 4; ++r)
        C[(size_t)(grow + r) * Nn + gcol] = f2b(acc[mi][ni][r] + bv_);
    }
  }
}

// ---------------- output GEMM: C f32 = A(bf16) * B(bf16)^T + bias ----------------
__global__ __launch_bounds__(256) void gemm_out(
    const unsigned short* __restrict__ A, const unsigned short* __restrict__ B,
    const float* __restrict__ bias, float* __restrict__ Cf, int M) {
  __shared__ __align__(16) unsigned short As[2][128 * 32];
  __shared__ __align__(16) unsigned short Bs[2][128 * 32];
  const int K = HID, Nn = HID;
  const int tid = threadIdx.x;
  const int lane = tid & 63;
  const int wid = tid >> 6;
  const int wr = wid >> 1, wc = wid & 1;
  const int l16 = lane & 15, kq = lane >> 4;

  int gx = gridDim.x, gy = gridDim.y;
  int nwg = gx * gy;
  int orig = blockIdx.y * gx + blockIdx.x;
  int bx, by;
  if ((nwg & 7) == 0) {
    int cpx = nwg >> 3;
    int swz = (orig & 7) * cpx + (orig >> 3);
    bx = swz / gy;
    by = swz - bx * gy;
  } else {
    bx = blockIdx.x;
    by = blockIdx.y;
  }
  const int m0 = bx * 128;
  const int n0 = by * 128;

  f32x4 acc[4][4];
#pragma unroll
  for (int i = 0; i < 4; ++i)
#pragma unroll
    for (int j = 0; j < 4; ++j) acc[i][j] = (f32x4){0.f, 0.f, 0.f, 0.f};

  const int srow = tid >> 2;
  const int skg = tid & 3;
  const int scol = (skg ^ ((srow >> 1) & 3)) * 8;
  const int sbase = (tid & ~63) * 8;

  const unsigned short* Ag = A + (size_t)(m0 + srow) * K + scol;
  const unsigned short* Bg = B + (size_t)(n0 + srow) * K + scol;
  const int kqA0 = (kq ^ ((l16 >> 1) & 3)) * 8;

#define STAGE(buf, kk)                                                                              \
  do {                                                                                              \
    __builtin_amdgcn_global_load_lds((const __attribute__((address_space(1))) void*)(Ag + (kk)),    \
                                     (__attribute__((address_space(3))) void*)(&As[buf][0] + sbase), 16, 0, 0); \
    __builtin_amdgcn_global_load_lds((const __attribute__((address_space(1))) void*)(Ag + (size_t)64 * K + (kk)), \
                                     (__attribute__((address_space(3))) void*)(&As[buf][0] + 2048 + sbase), 16, 0, 0); \
    __builtin_amdgcn_global_load_lds((const __attribute__((address_space(1))) void*)(Bg + (kk)),    \
                                     (__attribute__((address_space(3))) void*)(&Bs[buf][0] + sbase), 16, 0, 0); \
    __builtin_amdgcn_global_load_lds((const __attribute__((address_space(1))) void*)(Bg + (size_t)64 * K + (kk)), \
                                     (__attribute__((address_space(3))) void*)(&Bs[buf][0] + 2048 + sbase), 16, 0, 0); \
  } while (0)

  STAGE(0, 0);
  __syncthreads();
  int cur = 0;
  for (int k0 = 0; k0 < K; k0 += 32) {
    if (k0 + 32 < K) STAGE(cur ^ 1, k0 + 32);
    bf16x8 af[4], bfr[4];
#pragma unroll
    for (int i = 0; i < 4; ++i) {
      int ra = wr * 64 + i * 16 + l16;
      af[i] = *(const bf16x8*)(&As[cur][0] + ra * 32 + kqA0);
      int rb = wc * 64 + i * 16 + l16;
      bfr[i] = *(const bf16x8*)(&Bs[cur][0] + rb * 32 + kqA0);
    }
#pragma unroll
    for (int mi = 0; mi < 4; ++mi)
#pragma unroll
      for (int ni = 0; ni < 4; ++ni)
        acc[mi][ni] = __builtin_amdgcn_mfma_f32_16x16x32_bf16(af[mi], bfr[ni], acc[mi][ni], 0, 0, 0);
    __syncthreads();
    cur ^= 1;
  }
#undef STAGE

#pragma unroll
  for (int mi = 0; mi < 4; ++mi) {
    int grow = m0 + wr * 64 + mi * 16 + kq * 4;
#pragma unroll
    for (int ni = 0; ni < 4; ++ni) {
      int gcol = n0 + wc * 64 + ni * 16 + l16;
      float bv_ = bias[gcol];
#pragma unroll
      for (int r = 0; r < 4; ++r)
        Cf[(size_t)(grow + r) * Nn + gcol] = acc[mi][ni][r] + bv_;
    }
  }
}

// ---------------- rowptr from sorted row_idx ----------------
__global__ __launch_bounds__(256) void build_rowptr(const int* __restrict__ row_idx,
                                                    int* __restrict__ rowptr, int n, int E_) {
  int t = blockIdx.x * 256 + threadIdx.x;
  if (t > n) return;
  int lo = 0, hi = E_;
  while (lo < hi) {
    int mid = (lo + hi) >> 1;
    if (row_idx[mid] < t) lo = mid + 1; else hi = mid;
  }
  rowptr[t] = lo;
}

// head->XCD affinity: XCD = linear-block-id % 8 (m157-verified mapping). Remap so each
// XCD gets a CONTIGUOUS (head, chunk) span -> its L2 holds ONE 4.2MB head plane at a
// time instead of all 8 XCDs duplicating the same plane. Bijective (nblk % 8 == 0).
__device__ inline void xcd_affine(int gx, int& head, int& bx) {
  int L = blockIdx.y * gx + blockIdx.x;
  int nblk = gx * gridDim.y;
  int per = nblk >> 3;
  int j = (L & 7) * per + (L >> 3);
  head = j / gx;
  bx = j - head * gx;
}

// ---------------- pass A: edge-centric SDDMM (per head), packed-f32x2 dot ----------------
__global__ __launch_bounds__(256) void sddmm_ec(const int* __restrict__ row_idx,
                                                const int* __restrict__ col_idx,
                                                const unsigned short* __restrict__ q,
                                                const unsigned short* __restrict__ kv,
                                                float* __restrict__ scores, int E_) {
  int head, bx;
  xcd_affine(gridDim.x, head, bx);
  int lane = threadIdx.x & 63;
  int wid = threadIdx.x >> 6;
  int g = lane >> 3, dl = lane & 7;
  const unsigned short* qbase = q + head * HD + dl * 8;
  const unsigned short* kbase = kv + head * HD + dl * 8;
  float* sc = scores + (size_t)head * E_;
  int e00 = bx * 512 + wid * 128;
#pragma unroll
  for (int it = 0; it < 8; ++it) {
    int ea = e00 + it * 16 + g;
    int eb = ea + 8;
    int eac = ea < E_ ? ea : E_ - 1;
    int ebc = eb < E_ ? eb : E_ - 1;
    int ra = row_idx[eac], ca = col_idx[eac];
    int rb = row_idx[ebc], cb = col_idx[ebc];
    uint4 qa = *(const uint4*)(qbase + (size_t)ra * HID);
    uint4 ka = *(const uint4*)(kbase + (size_t)ca * (2 * HID));
    uint4 qb2 = *(const uint4*)(qbase + (size_t)rb * HID);
    uint4 kb = *(const uint4*)(kbase + (size_t)cb * (2 * HID));
    f32x2 d2a = {0.f, 0.f}, d2b = {0.f, 0.f};
    d2a += bf2f2(qa.x) * bf2f2(ka.x);
    d2a += bf2f2(qa.y) * bf2f2(ka.y);
    d2a += bf2f2(qa.z) * bf2f2(ka.z);
    d2a += bf2f2(qa.w) * bf2f2(ka.w);
    d2b += bf2f2(qb2.x) * bf2f2(kb.x);
    d2b += bf2f2(qb2.y) * bf2f2(kb.y);
    d2b += bf2f2(qb2.z) * bf2f2(kb.z);
    d2b += bf2f2(qb2.w) * bf2f2(kb.w);
    float da = d2a[0] + d2a[1];
    float db = d2b[0] + d2b[1];
    da += __shfl_xor(da, 1); db += __shfl_xor(db, 1);
    da += __shfl_xor(da, 2); db += __shfl_xor(db, 2);
    da += __shfl_xor(da, 4); db += __shfl_xor(db, 4);
    if (dl == 0) {
      if (ea < E_) sc[ea] = da;
      if (eb < E_) sc[eb] = db;
    }
  }
}

// ---------------- pass B: wave per (row, head); single-head working set (4.2MB/XCD) ----------------
// 64 lanes = 8 edge-groups x 8 dim-groups; independent per-lane EXP2; 16 edges in flight.
__global__ __launch_bounds__(256) void edge_spmm4(const int* __restrict__ rowptr,
                                                  const int* __restrict__ col_idx,
                                                  const float* __restrict__ scores,
                                                  const unsigned short* __restrict__ kv,
                                                  unsigned short* __restrict__ out, int n, int E_) {
  int head, bx;
  xcd_affine(gridDim.x, head, bx);
  int lane = threadIdx.x & 63;
  int row = bx * 4 + (threadIdx.x >> 6);
  if (row >= n) return;
  int g = lane >> 3, dl = lane & 7;
  int s0 = rowptr[row], s1 = rowptr[row + 1];
  const float* sc = scores + (size_t)head * E_;

  // row max + exp-sum: 64-lane coalesced sweeps over the contiguous segment
  float m = -1e30f;
  for (int e = s0 + lane; e < s1; e += 64) m = fmaxf(m, sc[e]);
  m = fmaxf(m, __shfl_xor(m, 1));
  m = fmaxf(m, __shfl_xor(m, 2));
  m = fmaxf(m, __shfl_xor(m, 4));
  m = fmaxf(m, __shfl_xor(m, 8));
  m = fmaxf(m, __shfl_xor(m, 16));
  m = fmaxf(m, __shfl_xor(m, 32));
  float sm = 0.f;
  for (int e = s0 + lane; e < s1; e += 64) sm += EXP2(sc[e] - m);
  sm += __shfl_xor(sm, 1);
  sm += __shfl_xor(sm, 2);
  sm += __shfl_xor(sm, 4);
  sm += __shfl_xor(sm, 8);
  sm += __shfl_xor(sm, 16);
  sm += __shfl_xor(sm, 32);
  float inv = (sm > 0.f) ? 1.f / sm : 0.f;

  const unsigned short* vbase = kv + HID + head * HD + dl * 8;
  f32x2 acc2[4] = {};
  int e0 = s0;
  for (; e0 + 16 <= s1; e0 += 16) {  // 2 independent 8-edge chains
    int ea = e0 + g, eb = e0 + 8 + g;
    int ca = col_idx[ea], cb = col_idx[eb];
    float wa = EXP2(sc[ea] - m);
    float wb = EXP2(sc[eb] - m);
    uint4 va = *(const uint4*)(vbase + (size_t)ca * (2 * HID));
    uint4 vb = *(const uint4*)(vbase + (size_t)cb * (2 * HID));
    acc2[0] += bf2f2(va.x) * wa; acc2[1] += bf2f2(va.y) * wa;
    acc2[2] += bf2f2(va.z) * wa; acc2[3] += bf2f2(va.w) * wa;
    acc2[0] += bf2f2(vb.x) * wb; acc2[1] += bf2f2(vb.y) * wb;
    acc2[2] += bf2f2(vb.z) * wb; acc2[3] += bf2f2(vb.w) * wb;
  }
  for (; e0 < s1; e0 += 8) {  // masked 8-edge tail
    int ea = e0 + g;
    bool valid = ea < s1;
    int ec = valid ? ea : s0;
    int c = col_idx[ec];
    float w = valid ? EXP2(sc[ec] - m) : 0.f;
    uint4 vv = *(const uint4*)(vbase + (size_t)c * (2 * HID));
    acc2[0] += bf2f2(vv.x) * w; acc2[1] += bf2f2(vv.y) * w;
    acc2[2] += bf2f2(vv.z) * w; acc2[3] += bf2f2(vv.w) * w;
  }
  // reduce over the 8 edge-groups (lane bits 3,4,5)
#pragma unroll
  for (int i = 0; i < 4; ++i) {
    acc2[i][0] += __shfl_xor(acc2[i][0], 8);
    acc2[i][1] += __shfl_xor(acc2[i][1], 8);
    acc2[i][0] += __shfl_xor(acc2[i][0], 16);
    acc2[i][1] += __shfl_xor(acc2[i][1], 16);
    acc2[i][0] += __shfl_xor(acc2[i][0], 32);
    acc2[i][1] += __shfl_xor(acc2[i][1], 32);
  }
  if (g == 0) {
    short o[8];
#pragma unroll
    for (int i = 0; i < 4; ++i) {
      o[2 * i] = (short)f2b(acc2[i][0] * inv);
      o[2 * i + 1] = (short)f2b(acc2[i][1] * inv);
    }
    *(bf16x8*)(out + (size_t)row * HID + head * HD + dl * 8) = *(bf16x8*)o;
  }
}

// ---------------- launch ----------------
extern "C" void kernel_launch(void* const* d_in, const int* in_sizes, int n_in,
                              void* d_out, int out_size, void* d_ws, size_t ws_size,
                              hipStream_t stream) {
  const float* h_source = (const float*)d_in[0];
  const float* h_target = (const float*)d_in[1];
  const int* row_idx = (const int*)d_in[2];
  const int* col_idx = (const int*)d_in[3];
  const float* Wq = (const float*)d_in[4];
  const float* bq = (const float*)d_in[5];
  const float* Wk = (const float*)d_in[6];
  const float* bk = (const float*)d_in[7];
  const float* Wv = (const float*)d_in[8];
  const float* bv = (const float*)d_in[9];
  const float* Wo = (const float*)d_in[10];
  const float* bo = (const float*)d_in[11];
  float* out = (float*)d_out;

  const int n = in_sizes[0] / HID;   // 32768
  const int E_ = in_sizes[2];        // 1048576

  char* ws = (char*)d_ws;
  size_t off = 0;
  auto alloc = [&](size_t bytes) -> void* {
    off = (off + 255) & ~(size_t)255;
    void* p = ws + off;
    off += bytes;
    return p;
  };
  unsigned short* htb = (unsigned short*)alloc((size_t)n * HID * 2);   // h_target bf16
  unsigned short* hsb = (unsigned short*)alloc((size_t)n * HID * 2);   // h_source bf16
  unsigned short* qb = (unsigned short*)alloc((size_t)n * HID * 2);    // q; attn_out in-place
  unsigned short* kvb = (unsigned short*)alloc((size_t)n * 2 * HID * 2);  // kv interleaved
  float* scores = (float*)alloc((size_t)NH * E_ * 4);                  // per-head planes
  unsigned short* wqp = (unsigned short*)alloc((size_t)HID * HID * 2);
  unsigned short* wkvp = (unsigned short*)alloc((size_t)2 * HID * HID * 2);
  unsigned short* wop = (unsigned short*)alloc((size_t)HID * HID * 2);
  float* bqp = (float*)alloc(HID * 4);
  float* bkvp = (float*)alloc(2 * HID * 4);
  int* rowptr = (int*)alloc((size_t)(n + 1) * 4);

  int n4 = n * HID / 4;
  cast_bf16_2<<<dim3((n4 + 255) / 256, 2), 256, 0, stream>>>(h_target, h_source, htb, hsb, n4);
  prep_weights<<<dim3(HID * HID / 256, 4), 256, 0, stream>>>(Wq, Wk, Wv, Wo, wqp, wkvp, wop);
  prep_bias<<<1, HID, 0, stream>>>(bq, bk, bv, bqp, bkvp);
  build_rowptr<<<(n + 1 + 255) / 256, 256, 0, stream>>>(row_idx, rowptr, n, E_);

  gemm_proj<<<dim3(n / 128, 18), 256, 0, stream>>>(htb, hsb, wqp, wkvp, bqp, bkvp, qb, kvb, n);

  dim3 ga((E_ + 511) / 512, NH);
  sddmm_ec<<<ga, 256, 0, stream>>>(row_idx, col_idx, qb, kvb, scores, E_);
  dim3 gb(n / 4, NH);
  edge_spmm4<<<gb, 256, 0, stream>>>(rowptr, col_idx, scores, kvb, qb /* attn_out */, n, E_);

  gemm_out<<<dim3(n / 128, 6), 256, 0, stream>>>(qb, wop, bo, out, n);
}

// Round 14
// 631.198 us; speedup vs baseline: 1.1072x; 1.1072x over previous
//
#include <hip/hip_runtime.h>

typedef __attribute__((ext_vector_type(8))) short bf16x8;
typedef __attribute__((ext_vector_type(4))) float f32x4;
typedef __attribute__((ext_vector_type(2))) float f32x2;

#define HID 768
#define NH 12
#define HD 64

#if defined(__has_builtin)
#  if __has_builtin(__builtin_amdgcn_exp2f)
#    define EXP2(x) __builtin_amdgcn_exp2f(x)
#  endif
#endif
#ifndef EXP2
#  define EXP2(x) exp2f(x)
#endif

// q pre-scale: HEAD_DIM^-0.5 * log2(e)  -> scores land in log2 domain
#define QSCALE 0.18033688011112042f

__device__ inline float b2f(unsigned short x) {
  return __builtin_bit_cast(float, ((unsigned)x) << 16);
}
__device__ inline unsigned short f2b(float f) {
  unsigned u = __builtin_bit_cast(unsigned, f);
  u += 0x7fffu + ((u >> 16) & 1u);  // RNE
  return (unsigned short)(u >> 16);
}
// one packed bf16 dword -> 2 floats
__device__ inline f32x2 bf2f2(unsigned d) {
  f32x2 r;
  r[0] = __builtin_bit_cast(float, d << 16);
  r[1] = __builtin_bit_cast(float, d & 0xFFFF0000u);
  return r;
}

// ---------------- cast fp32 -> bf16 (both tensors, one launch) ----------------
__global__ __launch_bounds__(256) void cast_bf16_2(const float* __restrict__ in0,
                                                   const float* __restrict__ in1,
                                                   unsigned short* __restrict__ out0,
                                                   unsigned short* __restrict__ out1, int n4) {
  int t = blockIdx.x * 256 + threadIdx.x;
  if (t >= n4) return;
  const float* in = blockIdx.y ? in1 : in0;
  unsigned short* out = blockIdx.y ? out1 : out0;
  float4 v = ((const float4*)in)[t];
  ushort4 o;
  o.x = f2b(v.x); o.y = f2b(v.y); o.z = f2b(v.z); o.w = f2b(v.w);
  ((ushort4*)out)[t] = o;
}

// ---------------- weight prep: permute rows to head-major, cast bf16 ----------------
__global__ __launch_bounds__(256) void prep_weights(
    const float* __restrict__ Wq, const float* __restrict__ Wk,
    const float* __restrict__ Wv, const float* __restrict__ Wo,
    unsigned short* __restrict__ wq, unsigned short* __restrict__ wkv,
    unsigned short* __restrict__ wo) {
  int mat = blockIdx.y;
  int o = blockIdx.x * 256 + threadIdx.x;  // < 768*768
  int jrow = o / HID, c = o - jrow * HID;
  if (mat < 3) {
    int h = jrow >> 6, d = jrow & 63;
    const float* W = (mat == 0) ? Wq : ((mat == 1) ? Wk : Wv);
    float val = W[(d * NH + h) * HID + c];
    if (mat == 0) {
      wq[o] = f2b(val * QSCALE);
    } else if (mat == 1) {
      wkv[o] = f2b(val);
    } else {
      wkv[(size_t)HID * HID + o] = f2b(val);
    }
  } else {
    int h = c >> 6, d = c & 63;
    wo[o] = f2b(Wo[(size_t)jrow * HID + d * NH + h]);
  }
}

__global__ void prep_bias(const float* __restrict__ bq, const float* __restrict__ bk,
                          const float* __restrict__ bv, float* __restrict__ bqp,
                          float* __restrict__ bkvp) {
  int j = threadIdx.x;
  if (j >= HID) return;
  int h = j >> 6, d = j & 63, s = d * NH + h;
  bqp[j] = bq[s] * QSCALE;
  bkvp[j] = bk[s];
  bkvp[HID + j] = bv[s];
}

// ---------------- fused projection GEMM: q (by<6, htb) + kv (by>=6, hsb), one dispatch ----------------
__global__ __launch_bounds__(256) void gemm_proj(
    const unsigned short* __restrict__ Aq, const unsigned short* __restrict__ Akv,
    const unsigned short* __restrict__ Bq, const unsigned short* __restrict__ Bkv,
    const float* __restrict__ biasq, const float* __restrict__ biaskv,
    unsigned short* __restrict__ Cq, unsigned short* __restrict__ Ckv, int M) {
  __shared__ __align__(16) unsigned short As[2][128 * 32];
  __shared__ __align__(16) unsigned short Bs[2][128 * 32];
  const int K = HID;
  const int tid = threadIdx.x;
  const int lane = tid & 63;
  const int wid = tid >> 6;
  const int wr = wid >> 1, wc = wid & 1;
  const int l16 = lane & 15, kq = lane >> 4;

  int gx = gridDim.x, gy = gridDim.y;
  int nwg = gx * gy;
  int orig = blockIdx.y * gx + blockIdx.x;
  int bx, by;
  if ((nwg & 7) == 0) {
    int cpx = nwg >> 3;
    int swz = (orig & 7) * cpx + (orig >> 3);
    bx = swz / gy;
    by = swz - bx * gy;
  } else {
    bx = blockIdx.x;
    by = blockIdx.y;
  }
  const unsigned short* A;
  const unsigned short* B;
  const float* bias;
  unsigned short* C;
  int Nn, n0;
  if (by < 6) {
    A = Aq; B = Bq; bias = biasq; C = Cq; Nn = HID; n0 = by * 128;
  } else {
    A = Akv; B = Bkv; bias = biaskv; C = Ckv; Nn = 2 * HID; n0 = (by - 6) * 128;
  }
  const int m0 = bx * 128;

  f32x4 acc[4][4];
#pragma unroll
  for (int i = 0; i < 4; ++i)
#pragma unroll
    for (int j = 0; j < 4; ++j) acc[i][j] = (f32x4){0.f, 0.f, 0.f, 0.f};

  const int srow = tid >> 2;
  const int skg = tid & 3;
  const int scol = (skg ^ ((srow >> 1) & 3)) * 8;
  const int sbase = (tid & ~63) * 8;

  const unsigned short* Ag = A + (size_t)(m0 + srow) * K + scol;
  const unsigned short* Bg = B + (size_t)(n0 + srow) * K + scol;
  const int kqA0 = (kq ^ ((l16 >> 1) & 3)) * 8;

#define STAGE(buf, kk)                                                                              \
  do {                                                                                              \
    __builtin_amdgcn_global_load_lds((const __attribute__((address_space(1))) void*)(Ag + (kk)),    \
                                     (__attribute__((address_space(3))) void*)(&As[buf][0] + sbase), 16, 0, 0); \
    __builtin_amdgcn_global_load_lds((const __attribute__((address_space(1))) void*)(Ag + (size_t)64 * K + (kk)), \
                                     (__attribute__((address_space(3))) void*)(&As[buf][0] + 2048 + sbase), 16, 0, 0); \
    __builtin_amdgcn_global_load_lds((const __attribute__((address_space(1))) void*)(Bg + (kk)),    \
                                     (__attribute__((address_space(3))) void*)(&Bs[buf][0] + sbase), 16, 0, 0); \
    __builtin_amdgcn_global_load_lds((const __attribute__((address_space(1))) void*)(Bg + (size_t)64 * K + (kk)), \
                                     (__attribute__((address_space(3))) void*)(&Bs[buf][0] + 2048 + sbase), 16, 0, 0); \
  } while (0)

  STAGE(0, 0);
  __syncthreads();
  int cur = 0;
  for (int k0 = 0; k0 < K; k0 += 32) {
    if (k0 + 32 < K) STAGE(cur ^ 1, k0 + 32);
    bf16x8 af[4], bfr[4];
#pragma unroll
    for (int i = 0; i < 4; ++i) {
      int ra = wr * 64 + i * 16 + l16;
      af[i] = *(const bf16x8*)(&As[cur][0] + ra * 32 + kqA0);
      int rb = wc * 64 + i * 16 + l16;
      bfr[i] = *(const bf16x8*)(&Bs[cur][0] + rb * 32 + kqA0);
    }
#pragma unroll
    for (int mi = 0; mi < 4; ++mi)
#pragma unroll
      for (int ni = 0; ni < 4; ++ni)
        acc[mi][ni] = __builtin_amdgcn_mfma_f32_16x16x32_bf16(af[mi], bfr[ni], acc[mi][ni], 0, 0, 0);
    __syncthreads();
    cur ^= 1;
  }
#undef STAGE

#pragma unroll
  for (int mi = 0; mi < 4; ++mi) {
    int grow = m0 + wr * 64 + mi * 16 + kq * 4;
#pragma unroll
    for (int ni = 0; ni < 4; ++ni) {
      int gcol = n0 + wc * 64 + ni * 16 + l16;
      float bv_ = bias[gcol];
#pragma unroll
      for (int r = 0; r < 4; ++r)
        C[(size_t)(grow + r) * Nn + gcol] = f2b(acc[mi][ni][r] + bv_);
    }
  }
}

// ---------------- output GEMM: C f32 = A(bf16) * B(bf16)^T + bias ----------------
__global__ __launch_bounds__(256) void gemm_out(
    const unsigned short* __restrict__ A, const unsigned short* __restrict__ B,
    const float* __restrict__ bias, float* __restrict__ Cf, int M) {
  __shared__ __align__(16) unsigned short As[2][128 * 32];
  __shared__ __align__(16) unsigned short Bs[2][128 * 32];
  const int K = HID, Nn = HID;
  const int tid = threadIdx.x;
  const int lane = tid & 63;
  const int wid = tid >> 6;
  const int wr = wid >> 1, wc = wid & 1;
  const int l16 = lane & 15, kq = lane >> 4;

  int gx = gridDim.x, gy = gridDim.y;
  int nwg = gx * gy;
  int orig = blockIdx.y * gx + blockIdx.x;
  int bx, by;
  if ((nwg & 7) == 0) {
    int cpx = nwg >> 3;
    int swz = (orig & 7) * cpx + (orig >> 3);
    bx = swz / gy;
    by = swz - bx * gy;
  } else {
    bx = blockIdx.x;
    by = blockIdx.y;
  }
  const int m0 = bx * 128;
  const int n0 = by * 128;

  f32x4 acc[4][4];
#pragma unroll
  for (int i = 0; i < 4; ++i)
#pragma unroll
    for (int j = 0; j < 4; ++j) acc[i][j] = (f32x4){0.f, 0.f, 0.f, 0.f};

  const int srow = tid >> 2;
  const int skg = tid & 3;
  const int scol = (skg ^ ((srow >> 1) & 3)) * 8;
  const int sbase = (tid & ~63) * 8;

  const unsigned short* Ag = A + (size_t)(m0 + srow) * K + scol;
  const unsigned short* Bg = B + (size_t)(n0 + srow) * K + scol;
  const int kqA0 = (kq ^ ((l16 >> 1) & 3)) * 8;

#define STAGE(buf, kk)                                                                              \
  do {                                                                                              \
    __builtin_amdgcn_global_load_lds((const __attribute__((address_space(1))) void*)(Ag + (kk)),    \
                                     (__attribute__((address_space(3))) void*)(&As[buf][0] + sbase), 16, 0, 0); \
    __builtin_amdgcn_global_load_lds((const __attribute__((address_space(1))) void*)(Ag + (size_t)64 * K + (kk)), \
                                     (__attribute__((address_space(3))) void*)(&As[buf][0] + 2048 + sbase), 16, 0, 0); \
    __builtin_amdgcn_global_load_lds((const __attribute__((address_space(1))) void*)(Bg + (kk)),    \
                                     (__attribute__((address_space(3))) void*)(&Bs[buf][0] + sbase), 16, 0, 0); \
    __builtin_amdgcn_global_load_lds((const __attribute__((address_space(1))) void*)(Bg + (size_t)64 * K + (kk)), \
                                     (__attribute__((address_space(3))) void*)(&Bs[buf][0] + 2048 + sbase), 16, 0, 0); \
  } while (0)

  STAGE(0, 0);
  __syncthreads();
  int cur = 0;
  for (int k0 = 0; k0 < K; k0 += 32) {
    if (k0 + 32 < K) STAGE(cur ^ 1, k0 + 32);
    bf16x8 af[4], bfr[4];
#pragma unroll
    for (int i = 0; i < 4; ++i) {
      int ra = wr * 64 + i * 16 + l16;
      af[i] = *(const bf16x8*)(&As[cur][0] + ra * 32 + kqA0);
      int rb = wc * 64 + i * 16 + l16;
      bfr[i] = *(const bf16x8*)(&Bs[cur][0] + rb * 32 + kqA0);
    }
#pragma unroll
    for (int mi = 0; mi < 4; ++mi)
#pragma unroll
      for (int ni = 0; ni < 4; ++ni)
        acc[mi][ni] = __builtin_amdgcn_mfma_f32_16x16x32_bf16(af[mi], bfr[ni], acc[mi][ni], 0, 0, 0);
    __syncthreads();
    cur ^= 1;
  }
#undef STAGE

#pragma unroll
  for (int mi = 0; mi < 4; ++mi) {
    int grow = m0 + wr * 64 + mi * 16 + kq * 4;
#pragma unroll
    for (int ni = 0; ni < 4; ++ni) {
      int gcol = n0 + wc * 64 + ni * 16 + l16;
      float bv_ = bias[gcol];
#pragma unroll
      for (int r = 0; r < 4; ++r)
        Cf[(size_t)(grow + r) * Nn + gcol] = acc[mi][ni][r] + bv_;
    }
  }
}

// ---------------- rowptr from sorted row_idx ----------------
__global__ __launch_bounds__(256) void build_rowptr(const int* __restrict__ row_idx,
                                                    int* __restrict__ rowptr, int n, int E_) {
  int t = blockIdx.x * 256 + threadIdx.x;
  if (t > n) return;
  int lo = 0, hi = E_;
  while (lo < hi) {
    int mid = (lo + hi) >> 1;
    if (row_idx[mid] < t) lo = mid + 1; else hi = mid;
  }
  rowptr[t] = lo;
}

// head->XCD affinity: XCD = linear-block-id % 8 (m157 mapping). Remap so each XCD
// gets a CONTIGUOUS (y, x) span -> its L2 holds one head (or pair) plane at a time
// instead of 8 XCDs duplicating the same plane. Bijective when nblk % 8 == 0.
// r13 evidence: spmm FETCH 535 -> 240 MB with this remap.
__device__ inline void xcd_affine(int gx, int& y, int& bx) {
  int L = blockIdx.y * gx + blockIdx.x;
  int nblk = gx * gridDim.y;
  int per = nblk >> 3;
  int j = (L & 7) * per + (L >> 3);
  y = j / gx;
  bx = j - y * gx;
}

// ---------------- pass A: edge-centric SDDMM (per head), packed-f32x2 dot, XCD affinity ----------------
__global__ __launch_bounds__(256) void sddmm_ec(const int* __restrict__ row_idx,
                                                const int* __restrict__ col_idx,
                                                const unsigned short* __restrict__ q,
                                                const unsigned short* __restrict__ kv,
                                                float* __restrict__ scores, int E_) {
  int head, bx;
  xcd_affine(gridDim.x, head, bx);
  int lane = threadIdx.x & 63;
  int wid = threadIdx.x >> 6;
  int g = lane >> 3, dl = lane & 7;
  const unsigned short* qbase = q + head * HD + dl * 8;
  const unsigned short* kbase = kv + head * HD + dl * 8;
  float* sc = scores + (size_t)head * E_;
  int e00 = bx * 512 + wid * 128;
#pragma unroll
  for (int it = 0; it < 8; ++it) {
    int ea = e00 + it * 16 + g;
    int eb = ea + 8;
    int eac = ea < E_ ? ea : E_ - 1;
    int ebc = eb < E_ ? eb : E_ - 1;
    int ra = row_idx[eac], ca = col_idx[eac];
    int rb = row_idx[ebc], cb = col_idx[ebc];
    uint4 qa = *(const uint4*)(qbase + (size_t)ra * HID);
    uint4 ka = *(const uint4*)(kbase + (size_t)ca * (2 * HID));
    uint4 qb2 = *(const uint4*)(qbase + (size_t)rb * HID);
    uint4 kb = *(const uint4*)(kbase + (size_t)cb * (2 * HID));
    f32x2 d2a = {0.f, 0.f}, d2b = {0.f, 0.f};
    d2a += bf2f2(qa.x) * bf2f2(ka.x);
    d2a += bf2f2(qa.y) * bf2f2(ka.y);
    d2a += bf2f2(qa.z) * bf2f2(ka.z);
    d2a += bf2f2(qa.w) * bf2f2(ka.w);
    d2b += bf2f2(qb2.x) * bf2f2(kb.x);
    d2b += bf2f2(qb2.y) * bf2f2(kb.y);
    d2b += bf2f2(qb2.z) * bf2f2(kb.z);
    d2b += bf2f2(qb2.w) * bf2f2(kb.w);
    float da = d2a[0] + d2a[1];
    float db = d2b[0] + d2b[1];
    da += __shfl_xor(da, 1); db += __shfl_xor(db, 1);
    da += __shfl_xor(da, 2); db += __shfl_xor(db, 2);
    da += __shfl_xor(da, 4); db += __shfl_xor(db, 4);
    if (dl == 0) {
      if (ea < E_) sc[ea] = da;
      if (eb < E_) sc[eb] = db;
    }
  }
}

// ---------------- pass B: r12's proven 2-heads-per-wave spmm + per-pair XCD affinity ----------------
__global__ __launch_bounds__(256) void edge_spmm2(const int* __restrict__ rowptr,
                                                  const int* __restrict__ col_idx,
                                                  const float* __restrict__ scores,
                                                  const unsigned short* __restrict__ kv,
                                                  unsigned short* __restrict__ out, int n, int E_) {
  int pair, bx;
  xcd_affine(gridDim.x, pair, bx);
  int lane = threadIdx.x & 63;
  int row = bx * 4 + (threadIdx.x >> 6);
  if (row >= n) return;
  int hh = lane >> 5;
  int head = pair * 2 + hh;
  int hl = lane & 31;
  int g = hl >> 3, dl = hl & 7;
  int s0 = rowptr[row], s1 = rowptr[row + 1];
  const float* sc = scores + (size_t)head * E_;

  float m = -1e30f;
  for (int e = s0 + hl; e < s1; e += 32) m = fmaxf(m, sc[e]);
  m = fmaxf(m, __shfl_xor(m, 1));
  m = fmaxf(m, __shfl_xor(m, 2));
  m = fmaxf(m, __shfl_xor(m, 4));
  m = fmaxf(m, __shfl_xor(m, 8));
  m = fmaxf(m, __shfl_xor(m, 16));
  float sm = 0.f;
  for (int e = s0 + hl; e < s1; e += 32) sm += EXP2(sc[e] - m);
  sm += __shfl_xor(sm, 1);
  sm += __shfl_xor(sm, 2);
  sm += __shfl_xor(sm, 4);
  sm += __shfl_xor(sm, 8);
  sm += __shfl_xor(sm, 16);
  float inv = (sm > 0.f) ? 1.f / sm : 0.f;

  const unsigned short* vbase = kv + HID + head * HD + dl * 8;
  f32x2 acc2[4] = {};
  int e0 = s0;
  for (; e0 + 16 <= s1; e0 += 16) {
    int ea = e0 + g, eb = e0 + 4 + g, ec = e0 + 8 + g, ed = e0 + 12 + g;
    int ca = col_idx[ea], cb = col_idx[eb], cc = col_idx[ec], cd = col_idx[ed];
    float wa = EXP2(sc[ea] - m);
    float wb = EXP2(sc[eb] - m);
    float wc_ = EXP2(sc[ec] - m);
    float wd = EXP2(sc[ed] - m);
    uint4 va = *(const uint4*)(vbase + (size_t)ca * (2 * HID));
    uint4 vb = *(const uint4*)(vbase + (size_t)cb * (2 * HID));
    uint4 vc = *(const uint4*)(vbase + (size_t)cc * (2 * HID));
    uint4 vd = *(const uint4*)(vbase + (size_t)cd * (2 * HID));
    acc2[0] += bf2f2(va.x) * wa; acc2[1] += bf2f2(va.y) * wa;
    acc2[2] += bf2f2(va.z) * wa; acc2[3] += bf2f2(va.w) * wa;
    acc2[0] += bf2f2(vb.x) * wb; acc2[1] += bf2f2(vb.y) * wb;
    acc2[2] += bf2f2(vb.z) * wb; acc2[3] += bf2f2(vb.w) * wb;
    acc2[0] += bf2f2(vc.x) * wc_; acc2[1] += bf2f2(vc.y) * wc_;
    acc2[2] += bf2f2(vc.z) * wc_; acc2[3] += bf2f2(vc.w) * wc_;
    acc2[0] += bf2f2(vd.x) * wd; acc2[1] += bf2f2(vd.y) * wd;
    acc2[2] += bf2f2(vd.z) * wd; acc2[3] += bf2f2(vd.w) * wd;
  }
  if (e0 + 8 <= s1) {
    int ea = e0 + g, eb = e0 + 4 + g;
    int ca = col_idx[ea], cb = col_idx[eb];
    float wa = EXP2(sc[ea] - m);
    float wb = EXP2(sc[eb] - m);
    uint4 va = *(const uint4*)(vbase + (size_t)ca * (2 * HID));
    uint4 vb = *(const uint4*)(vbase + (size_t)cb * (2 * HID));
    acc2[0] += bf2f2(va.x) * wa; acc2[1] += bf2f2(va.y) * wa;
    acc2[2] += bf2f2(va.z) * wa; acc2[3] += bf2f2(va.w) * wa;
    acc2[0] += bf2f2(vb.x) * wb; acc2[1] += bf2f2(vb.y) * wb;
    acc2[2] += bf2f2(vb.z) * wb; acc2[3] += bf2f2(vb.w) * wb;
    e0 += 8;
  }
  for (; e0 < s1; e0 += 4) {
    int ea = e0 + g;
    bool valid = ea < s1;
    int ec = valid ? ea : s0;
    int c = col_idx[ec];
    float w = valid ? EXP2(sc[ec] - m) : 0.f;
    uint4 vv = *(const uint4*)(vbase + (size_t)c * (2 * HID));
    acc2[0] += bf2f2(vv.x) * w; acc2[1] += bf2f2(vv.y) * w;
    acc2[2] += bf2f2(vv.z) * w; acc2[3] += bf2f2(vv.w) * w;
  }
#pragma unroll
  for (int i = 0; i < 4; ++i) {
    acc2[i][0] += __shfl_xor(acc2[i][0], 8);
    acc2[i][1] += __shfl_xor(acc2[i][1], 8);
    acc2[i][0] += __shfl_xor(acc2[i][0], 16);
    acc2[i][1] += __shfl_xor(acc2[i][1], 16);
  }
  if (g == 0) {
    short o[8];
#pragma unroll
    for (int i = 0; i < 4; ++i) {
      o[2 * i] = (short)f2b(acc2[i][0] * inv);
      o[2 * i + 1] = (short)f2b(acc2[i][1] * inv);
    }
    *(bf16x8*)(out + (size_t)row * HID + head * HD + dl * 8) = *(bf16x8*)o;
  }
}

// ---------------- launch ----------------
extern "C" void kernel_launch(void* const* d_in, const int* in_sizes, int n_in,
                              void* d_out, int out_size, void* d_ws, size_t ws_size,
                              hipStream_t stream) {
  const float* h_source = (const float*)d_in[0];
  const float* h_target = (const float*)d_in[1];
  const int* row_idx = (const int*)d_in[2];
  const int* col_idx = (const int*)d_in[3];
  const float* Wq = (const float*)d_in[4];
  const float* bq = (const float*)d_in[5];
  const float* Wk = (const float*)d_in[6];
  const float* bk = (const float*)d_in[7];
  const float* Wv = (const float*)d_in[8];
  const float* bv = (const float*)d_in[9];
  const float* Wo = (const float*)d_in[10];
  const float* bo = (const float*)d_in[11];
  float* out = (float*)d_out;

  const int n = in_sizes[0] / HID;   // 32768
  const int E_ = in_sizes[2];        // 1048576

  char* ws = (char*)d_ws;
  size_t off = 0;
  auto alloc = [&](size_t bytes) -> void* {
    off = (off + 255) & ~(size_t)255;
    void* p = ws + off;
    off += bytes;
    return p;
  };
  unsigned short* htb = (unsigned short*)alloc((size_t)n * HID * 2);   // h_target bf16
  unsigned short* hsb = (unsigned short*)alloc((size_t)n * HID * 2);   // h_source bf16
  unsigned short* qb = (unsigned short*)alloc((size_t)n * HID * 2);    // q; attn_out in-place
  unsigned short* kvb = (unsigned short*)alloc((size_t)n * 2 * HID * 2);  // kv interleaved
  float* scores = (float*)alloc((size_t)NH * E_ * 4);                  // per-head planes
  unsigned short* wqp = (unsigned short*)alloc((size_t)HID * HID * 2);
  unsigned short* wkvp = (unsigned short*)alloc((size_t)2 * HID * HID * 2);
  unsigned short* wop = (unsigned short*)alloc((size_t)HID * HID * 2);
  float* bqp = (float*)alloc(HID * 4);
  float* bkvp = (float*)alloc(2 * HID * 4);
  int* rowptr = (int*)alloc((size_t)(n + 1) * 4);

  int n4 = n * HID / 4;
  cast_bf16_2<<<dim3((n4 + 255) / 256, 2), 256, 0, stream>>>(h_target, h_source, htb, hsb, n4);
  prep_weights<<<dim3(HID * HID / 256, 4), 256, 0, stream>>>(Wq, Wk, Wv, Wo, wqp, wkvp, wop);
  prep_bias<<<1, HID, 0, stream>>>(bq, bk, bv, bqp, bkvp);
  build_rowptr<<<(n + 1 + 255) / 256, 256, 0, stream>>>(row_idx, rowptr, n, E_);

  gemm_proj<<<dim3(n / 128, 18), 256, 0, stream>>>(htb, hsb, wqp, wkvp, bqp, bkvp, qb, kvb, n);

  dim3 ga((E_ + 511) / 512, NH);
  sddmm_ec<<<ga, 256, 0, stream>>>(row_idx, col_idx, qb, kvb, scores, E_);
  dim3 gb(n / 4, NH / 2);
  edge_spmm2<<<gb, 256, 0, stream>>>(rowptr, col_idx, scores, kvb, qb /* attn_out */, n, E_);

  gemm_out<<<dim3(n / 128, 6), 256, 0, stream>>>(qb, wop, bo, out, n);
}